// Round 1
// baseline (17.960 us; speedup 1.0000x reference)
//
#include <hip/hip_runtime.h>
#include <math.h>

#define BATCH 4096
#define IMGD 192
#define HC 64
#define PADV 6
#define NBLK 16  // BATCH / 256

// ---------------- K1: gather conv patches ----------------
// patch layout in ws: patch1[b][9] at [0, BATCH*9), patch2[b][9] at [BATCH*9, 2*BATCH*9)
__global__ void k_patches(const float* __restrict__ x, const int* __restrict__ ij,
                          const float* __restrict__ cw, const float* __restrict__ cb,
                          float* __restrict__ patch)
{
    int tid = blockIdx.x * blockDim.x + threadIdx.x;
    if (tid >= BATCH * 18) return;
    int b = tid / 18;
    int p = tid - b * 18;
    int r = p / 6;
    int c = p - r * 6;
    int i0 = ij[2 * b], j0 = ij[2 * b + 1];
    int rr = i0 - PADV + r; if (rr < 0) rr += HC;   // i0 in [0,64), r in [0,3)
    int cc = j0 - PADV + c; if (cc < 0) cc += HC;   // j0 in [0,64), c in [0,6)
    const float* xb = x + (size_t)b * IMGD * IMGD + (size_t)(rr * 3) * IMGD + cc * 3;
    float v = cb[0];
    v += xb[0]          * cw[0] + xb[1]            * cw[1] + xb[2]            * cw[2];
    v += xb[IMGD]       * cw[3] + xb[IMGD + 1]     * cw[4] + xb[IMGD + 2]     * cw[5];
    v += xb[2 * IMGD]   * cw[6] + xb[2 * IMGD + 1] * cw[7] + xb[2 * IMGD + 2] * cw[8];
    int half = (c >= 3) ? 1 : 0;
    int cl = c - 3 * half;
    patch[(size_t)half * (BATCH * 9) + (size_t)b * 9 + r * 3 + cl] = v;
}

// ---------------- K2: MI nets + block reduction ----------------
// LDS weight layout offsets:
//  xw1@0(81) xb1@81(9) xw2@90(81) xb2@171(9) xw3@180(135) xb3@315(15)
//  yw1@330   yb1@411   yw2@420    yb2@501    yw3@510      yb3@645
//  fw@660(15) fb@675(1)
__device__ __forceinline__ void branch9(const float* __restrict__ s, int off,
                                        const float* __restrict__ p, float out[15])
{
    float v[9];
    #pragma unroll
    for (int j = 0; j < 9; ++j) {
        float a = s[off + 81 + j];
        #pragma unroll
        for (int k = 0; k < 9; ++k) a += p[k] * s[off + j * 9 + k];
        v[j] = p[j] + fmaxf(a, 0.0f);
    }
    float u[9];
    #pragma unroll
    for (int j = 0; j < 9; ++j) {
        float a = s[off + 171 + j];
        #pragma unroll
        for (int k = 0; k < 9; ++k) a += v[k] * s[off + 90 + j * 9 + k];
        u[j] = v[j] + fmaxf(a, 0.0f);
    }
    #pragma unroll
    for (int j = 0; j < 15; ++j) {
        float a = s[off + 315 + j];
        #pragma unroll
        for (int k = 0; k < 9; ++k) a += u[k] * s[off + 180 + j * 9 + k];
        out[j] = a;
    }
}

__global__ __launch_bounds__(256) void k_minet(
    const float* __restrict__ patch, const int* __restrict__ perm,
    const float* __restrict__ xw1, const float* __restrict__ xb1,
    const float* __restrict__ xw2, const float* __restrict__ xb2,
    const float* __restrict__ xw3, const float* __restrict__ xb3,
    const float* __restrict__ yw1, const float* __restrict__ yb1,
    const float* __restrict__ yw2, const float* __restrict__ yb2,
    const float* __restrict__ yw3, const float* __restrict__ yb3,
    const float* __restrict__ fw, const float* __restrict__ fb,
    float* __restrict__ partials)  // partials[0..15]=sum(pred_xy), [16..31]=sum(exp(pred_x_y))
{
    __shared__ float s[676];
    __shared__ float r1[4], r2[4];
    int t = threadIdx.x;
    for (int i = t; i < 81; i += 256)  { s[i] = xw1[i];        s[330 + i] = yw1[i]; }
    for (int i = t; i < 81; i += 256)  { s[90 + i] = xw2[i];   s[420 + i] = yw2[i]; }
    for (int i = t; i < 135; i += 256) { s[180 + i] = xw3[i];  s[510 + i] = yw3[i]; }
    for (int i = t; i < 9; i += 256)   { s[81 + i] = xb1[i];   s[171 + i] = xb2[i];
                                         s[411 + i] = yb1[i];  s[501 + i] = yb2[i]; }
    for (int i = t; i < 15; i += 256)  { s[315 + i] = xb3[i];  s[645 + i] = yb3[i];
                                         s[660 + i] = fw[i]; }
    if (t == 0) s[675] = fb[0];
    __syncthreads();

    int b = blockIdx.x * 256 + t;
    const float* P1 = patch;
    const float* P2 = patch + BATCH * 9;
    int pb = perm[b];
    float p1[9], p2[9], p2s[9];
    #pragma unroll
    for (int i = 0; i < 9; ++i) {
        p1[i]  = P1[(size_t)b * 9 + i];
        p2[i]  = P2[(size_t)b * 9 + i];
        p2s[i] = P2[(size_t)pb * 9 + i];
    }

    float ox[15], oy[15], oys[15];
    branch9(s, 0,   p1,  ox);
    branch9(s, 330, p2,  oy);
    branch9(s, 330, p2s, oys);

    float fbv = s[675];
    float pxy = fbv, pxs = fbv;
    #pragma unroll
    for (int j = 0; j < 15; ++j) {
        pxy += fmaxf(ox[j] + oy[j],  0.0f) * s[660 + j];
        pxs += fmaxf(ox[j] + oys[j], 0.0f) * s[660 + j];
    }
    float e = expf(pxs);

    // wave (64-lane) reduction, then cross-wave via LDS — deterministic tree
    #pragma unroll
    for (int o = 32; o > 0; o >>= 1) {
        pxy += __shfl_down(pxy, o);
        e   += __shfl_down(e, o);
    }
    int wid = t >> 6, lane = t & 63;
    if (lane == 0) { r1[wid] = pxy; r2[wid] = e; }
    __syncthreads();
    if (t == 0) {
        partials[blockIdx.x]        = (r1[0] + r1[1]) + (r1[2] + r1[3]);
        partials[NBLK + blockIdx.x] = (r2[0] + r2[1]) + (r2[2] + r2[3]);
    }
}

// ---------------- K3: finalize ----------------
__global__ void k_final(const float* __restrict__ partials, float* __restrict__ out)
{
    float sx = 0.0f, se = 0.0f;
    for (int i = 0; i < NBLK; ++i) { sx += partials[i]; se += partials[NBLK + i]; }
    out[0] = logf(se / (float)BATCH) - sx / (float)BATCH;
}

extern "C" void kernel_launch(void* const* d_in, const int* in_sizes, int n_in,
                              void* d_out, int out_size, void* d_ws, size_t ws_size,
                              hipStream_t stream)
{
    const float* x    = (const float*)d_in[0];
    const int*   ij   = (const int*)d_in[1];
    const int*   perm = (const int*)d_in[2];
    const float* cw   = (const float*)d_in[3];
    const float* cb   = (const float*)d_in[4];
    const float* xw1  = (const float*)d_in[5];
    const float* xb1  = (const float*)d_in[6];
    const float* xw2  = (const float*)d_in[7];
    const float* xb2  = (const float*)d_in[8];
    const float* xw3  = (const float*)d_in[9];
    const float* xb3  = (const float*)d_in[10];
    const float* yw1  = (const float*)d_in[11];
    const float* yb1  = (const float*)d_in[12];
    const float* yw2  = (const float*)d_in[13];
    const float* yb2  = (const float*)d_in[14];
    const float* yw3  = (const float*)d_in[15];
    const float* yb3  = (const float*)d_in[16];
    const float* fw   = (const float*)d_in[17];
    const float* fb   = (const float*)d_in[18];

    float* ws_f     = (float*)d_ws;
    float* patch    = ws_f;                       // 2*BATCH*9 floats = 294912 B
    float* partials = ws_f + 2 * BATCH * 9;       // 32 floats

    int n1 = BATCH * 18;
    k_patches<<<(n1 + 255) / 256, 256, 0, stream>>>(x, ij, cw, cb, patch);
    k_minet<<<NBLK, 256, 0, stream>>>(patch, perm,
                                      xw1, xb1, xw2, xb2, xw3, xb3,
                                      yw1, yb1, yw2, yb2, yw3, yb3,
                                      fw, fb, partials);
    k_final<<<1, 1, 0, stream>>>(partials, (float*)d_out);
}

// Round 2
// 16.947 us; speedup vs baseline: 1.0597x; 1.0597x over previous
//
#include <hip/hip_runtime.h>
#include <math.h>

#define BATCH 4096
#define IMGD 192
#define HC 64
#define PADV 6
#define NBLK 64   // BATCH / 64, one wave per block

// ---- one 3x3 stride-3 conv output at image pointer xb (row-major, stride IMGD)
__device__ __forceinline__ float conv9(const float* __restrict__ xb,
                                       const float w[9], float bias)
{
    float v = bias;
    v += xb[0]            * w[0] + xb[1]            * w[1] + xb[2]            * w[2];
    v += xb[IMGD]         * w[3] + xb[IMGD + 1]     * w[4] + xb[IMGD + 2]     * w[5];
    v += xb[2 * IMGD]     * w[6] + xb[2 * IMGD + 1] * w[7] + xb[2 * IMGD + 2] * w[8];
    return v;
}

// LDS weight layout offsets:
//  xw1@0(81) xb1@81(9) xw2@90(81) xb2@171(9) xw3@180(135) xb3@315(15)
//  yw1@330   yb1@411   yw2@420    yb2@501    yw3@510      yb3@645
//  fw@660(15) fb@675(1)
__device__ __forceinline__ void branch9(const float* __restrict__ s, int off,
                                        const float* __restrict__ p, float out[15])
{
    float v[9];
    #pragma unroll
    for (int j = 0; j < 9; ++j) {
        float a = s[off + 81 + j];
        #pragma unroll
        for (int k = 0; k < 9; ++k) a += p[k] * s[off + j * 9 + k];
        v[j] = p[j] + fmaxf(a, 0.0f);
    }
    float u[9];
    #pragma unroll
    for (int j = 0; j < 9; ++j) {
        float a = s[off + 171 + j];
        #pragma unroll
        for (int k = 0; k < 9; ++k) a += v[k] * s[off + 90 + j * 9 + k];
        u[j] = v[j] + fmaxf(a, 0.0f);
    }
    #pragma unroll
    for (int j = 0; j < 15; ++j) {
        float a = s[off + 315 + j];
        #pragma unroll
        for (int k = 0; k < 9; ++k) a += u[k] * s[off + 180 + j * 9 + k];
        out[j] = a;
    }
}

__global__ __launch_bounds__(64) void k_fused(
    const float* __restrict__ x, const int* __restrict__ ij,
    const int* __restrict__ perm,
    const float* __restrict__ cw, const float* __restrict__ cb,
    const float* __restrict__ xw1, const float* __restrict__ xb1,
    const float* __restrict__ xw2, const float* __restrict__ xb2,
    const float* __restrict__ xw3, const float* __restrict__ xb3,
    const float* __restrict__ yw1, const float* __restrict__ yb1,
    const float* __restrict__ yw2, const float* __restrict__ yb2,
    const float* __restrict__ yw3, const float* __restrict__ yb3,
    const float* __restrict__ fw, const float* __restrict__ fb,
    float* __restrict__ partials)  // [0..63]=sum(pred_xy), [64..127]=sum(exp(pred_x_y))
{
    __shared__ float s[676];
    int t = threadIdx.x;
    for (int i = t; i < 81; i += 64)  { s[i] = xw1[i];        s[330 + i] = yw1[i];
                                        s[90 + i] = xw2[i];   s[420 + i] = yw2[i]; }
    for (int i = t; i < 135; i += 64) { s[180 + i] = xw3[i];  s[510 + i] = yw3[i]; }
    if (t < 9)  { s[81 + t] = xb1[t];   s[171 + t] = xb2[t];
                  s[411 + t] = yb1[t];  s[501 + t] = yb2[t]; }
    if (t < 15) { s[315 + t] = xb3[t];  s[645 + t] = yb3[t];  s[660 + t] = fw[t]; }
    if (t == 0) s[675] = fb[0];
    __syncthreads();

    int b  = blockIdx.x * 64 + t;
    int pb = perm[b];

    float w[9];
    #pragma unroll
    for (int i = 0; i < 9; ++i) w[i] = cw[i];   // uniform -> scalar loads
    float cbias = cb[0];

    int i0  = ij[2 * b],  j0  = ij[2 * b + 1];
    int i0p = ij[2 * pb], j0p = ij[2 * pb + 1];

    const float* xb0 = x + (size_t)b  * (IMGD * IMGD);
    const float* xbp = x + (size_t)pb * (IMGD * IMGD);

    float p1[9], p2[9], p2s[9];
    #pragma unroll
    for (int r = 0; r < 3; ++r) {
        int rr = i0 - PADV + r;  if (rr < 0) rr += HC;
        const float* xr = xb0 + (size_t)(rr * 3) * IMGD;
        #pragma unroll
        for (int c = 0; c < 6; ++c) {
            int cc = j0 - PADV + c;  if (cc < 0) cc += HC;
            float v = conv9(xr + cc * 3, w, cbias);
            if (c < 3) p1[r * 3 + c] = v; else p2[r * 3 + (c - 3)] = v;
        }
        int rrp = i0p - PADV + r;  if (rrp < 0) rrp += HC;
        const float* xrp = xbp + (size_t)(rrp * 3) * IMGD;
        #pragma unroll
        for (int c = 3; c < 6; ++c) {
            int cc = j0p - PADV + c;  if (cc < 0) cc += HC;
            p2s[r * 3 + (c - 3)] = conv9(xrp + cc * 3, w, cbias);
        }
    }

    float ox[15], oy[15], oys[15];
    branch9(s, 0,   p1,  ox);
    branch9(s, 330, p2,  oy);
    branch9(s, 330, p2s, oys);

    float fbv = s[675];
    float pxy = fbv, pxs = fbv;
    #pragma unroll
    for (int j = 0; j < 15; ++j) {
        pxy += fmaxf(ox[j] + oy[j],  0.0f) * s[660 + j];
        pxs += fmaxf(ox[j] + oys[j], 0.0f) * s[660 + j];
    }
    float e = expf(pxs);

    // 64-lane deterministic butterfly
    #pragma unroll
    for (int o = 32; o > 0; o >>= 1) {
        pxy += __shfl_down(pxy, o);
        e   += __shfl_down(e, o);
    }
    if (t == 0) {
        partials[blockIdx.x]        = pxy;
        partials[NBLK + blockIdx.x] = e;
    }
}

// ---------------- finalize: 1 block, 64 lanes ----------------
__global__ __launch_bounds__(64) void k_final(const float* __restrict__ partials,
                                              float* __restrict__ out)
{
    int t = threadIdx.x;
    float sx = partials[t];
    float se = partials[NBLK + t];
    #pragma unroll
    for (int o = 32; o > 0; o >>= 1) {
        sx += __shfl_down(sx, o);
        se += __shfl_down(se, o);
    }
    if (t == 0) out[0] = logf(se / (float)BATCH) - sx / (float)BATCH;
}

extern "C" void kernel_launch(void* const* d_in, const int* in_sizes, int n_in,
                              void* d_out, int out_size, void* d_ws, size_t ws_size,
                              hipStream_t stream)
{
    const float* x    = (const float*)d_in[0];
    const int*   ij   = (const int*)d_in[1];
    const int*   perm = (const int*)d_in[2];
    const float* cw   = (const float*)d_in[3];
    const float* cb   = (const float*)d_in[4];
    const float* xw1  = (const float*)d_in[5];
    const float* xb1  = (const float*)d_in[6];
    const float* xw2  = (const float*)d_in[7];
    const float* xb2  = (const float*)d_in[8];
    const float* xw3  = (const float*)d_in[9];
    const float* xb3  = (const float*)d_in[10];
    const float* yw1  = (const float*)d_in[11];
    const float* yb1  = (const float*)d_in[12];
    const float* yw2  = (const float*)d_in[13];
    const float* yb2  = (const float*)d_in[14];
    const float* yw3  = (const float*)d_in[15];
    const float* yb3  = (const float*)d_in[16];
    const float* fw   = (const float*)d_in[17];
    const float* fb   = (const float*)d_in[18];

    float* partials = (float*)d_ws;   // 128 floats, fully overwritten each launch

    k_fused<<<NBLK, 64, 0, stream>>>(x, ij, perm, cw, cb,
                                     xw1, xb1, xw2, xb2, xw3, xb3,
                                     yw1, yb1, yw2, yb2, yw3, yb3,
                                     fw, fb, partials);
    k_final<<<1, 64, 0, stream>>>(partials, (float*)d_out);
}

// Round 3
// 14.565 us; speedup vs baseline: 1.2330x; 1.1635x over previous
//
#include <hip/hip_runtime.h>
#include <math.h>

#define BATCH 4096
#define IMGD 192
#define HC 64
#define PADV 6
#define NBLK 64        // blocks; each handles 64 batch items with 256 threads
#define ITEMS 64       // items per block

// LDS weight layout offsets (floats):
//  xw1@0(81) xb1@81(9) xw2@90(81) xb2@171(9) xw3@180(135) xb3@315(15)
//  yw1@330   yb1@411   yw2@420    yb2@501    yw3@510      yb3@645
//  fw@660(15) fb@675(1)
__device__ __forceinline__ void branch9(const float* __restrict__ s, int off,
                                        const float* __restrict__ p, float* __restrict__ out)
{
    float v[9];
    #pragma unroll
    for (int j = 0; j < 9; ++j) {
        float a = s[off + 81 + j];
        #pragma unroll
        for (int k = 0; k < 9; ++k) a += p[k] * s[off + j * 9 + k];
        v[j] = p[j] + fmaxf(a, 0.0f);
    }
    float u[9];
    #pragma unroll
    for (int j = 0; j < 9; ++j) {
        float a = s[off + 171 + j];
        #pragma unroll
        for (int k = 0; k < 9; ++k) a += v[k] * s[off + 90 + j * 9 + k];
        u[j] = v[j] + fmaxf(a, 0.0f);
    }
    #pragma unroll
    for (int j = 0; j < 15; ++j) {
        float a = s[off + 315 + j];
        #pragma unroll
        for (int k = 0; k < 9; ++k) a += u[k] * s[off + 180 + j * 9 + k];
        out[j] = a;
    }
}

__global__ __launch_bounds__(256) void k_fused(
    const float* __restrict__ x, const int* __restrict__ ij,
    const int* __restrict__ perm,
    const float* __restrict__ cw, const float* __restrict__ cb,
    const float* __restrict__ xw1, const float* __restrict__ xb1,
    const float* __restrict__ xw2, const float* __restrict__ xb2,
    const float* __restrict__ xw3, const float* __restrict__ xb3,
    const float* __restrict__ yw1, const float* __restrict__ yb1,
    const float* __restrict__ yw2, const float* __restrict__ yb2,
    const float* __restrict__ yw3, const float* __restrict__ yb3,
    const float* __restrict__ fw, const float* __restrict__ fb,
    float* __restrict__ partials)  // [0..63]=sum(pred_xy), [64..127]=sum(exp(pred_x_y))
{
    __shared__ float s[676];
    __shared__ float lpatch[ITEMS * 27];   // [item][slot] slot: 0..8 p1, 9..17 p2, 18..26 p2s
    __shared__ float bout[192 * 15];       // [branch*64+item][15]

    int t = threadIdx.x;

    // ---- phase 0: weights -> LDS ----
    for (int i = t; i < 81; i += 256)  { s[i] = xw1[i];        s[330 + i] = yw1[i];
                                         s[90 + i] = xw2[i];   s[420 + i] = yw2[i]; }
    for (int i = t; i < 135; i += 256) { s[180 + i] = xw3[i];  s[510 + i] = yw3[i]; }
    if (t < 9)  { s[81 + t] = xb1[t];   s[171 + t] = xb2[t];
                  s[411 + t] = yb1[t];  s[501 + t] = yb2[t]; }
    if (t < 15) { s[315 + t] = xb3[t];  s[645 + t] = yb3[t];  s[660 + t] = fw[t]; }
    if (t == 0) s[675] = fb[0];

    float w[9];
    #pragma unroll
    for (int i = 0; i < 9; ++i) w[i] = cw[i];   // uniform addr -> scalar loads
    float cbias = cb[0];

    int b0 = blockIdx.x * ITEMS;

    // ---- phase 1: coalesced gather, one thread per conv output ----
    for (int idx = t; idx < ITEMS * 27; idx += 256) {
        int item = idx / 27;
        int p    = idx - item * 27;
        int bb, r, c, slot;
        if (p < 18) {
            bb = b0 + item;
            r = p / 6;  c = p - r * 6;
            int half = (c >= 3) ? 1 : 0;
            slot = half * 9 + r * 3 + (c - 3 * half);
        } else {
            int q = p - 18;
            bb = perm[b0 + item];
            r = q / 3;  c = 3 + (q - r * 3);
            slot = 18 + q;
        }
        int i0 = ij[2 * bb], j0 = ij[2 * bb + 1];
        int rr = i0 - PADV + r;  if (rr < 0) rr += HC;
        int cc = j0 - PADV + c;  if (cc < 0) cc += HC;
        const float* xp = x + (size_t)bb * (IMGD * IMGD)
                            + (size_t)(rr * 3) * IMGD + cc * 3;
        float v = cbias;
        v += xp[0]          * w[0] + xp[1]            * w[1] + xp[2]            * w[2];
        v += xp[IMGD]       * w[3] + xp[IMGD + 1]     * w[4] + xp[IMGD + 2]     * w[5];
        v += xp[2 * IMGD]   * w[6] + xp[2 * IMGD + 1] * w[7] + xp[2 * IMGD + 2] * w[8];
        lpatch[item * 27 + slot] = v;
    }
    __syncthreads();

    // ---- phase 2: 3 branch evals per item, wave-uniform branch selection ----
    if (t < 192) {
        int item   = t & 63;
        int branch = t >> 6;              // 0: x(p1), 1: y(p2), 2: y(p2s)
        int woff   = (branch == 0) ? 0 : 330;
        int pbase  = item * 27 + branch * 9;
        float p[9];
        #pragma unroll
        for (int k = 0; k < 9; ++k) p[k] = lpatch[pbase + k];
        float o[15];
        branch9(s, woff, p, o);
        #pragma unroll
        for (int j = 0; j < 15; ++j) bout[t * 15 + j] = o[j];
    }
    __syncthreads();

    // ---- phase 3: head + exp + wave reduction (wave 0 only) ----
    if (t < 64) {
        float fbv = s[675];
        float pxy = fbv, pxs = fbv;
        #pragma unroll
        for (int j = 0; j < 15; ++j) {
            float oxj  = bout[t * 15 + j];
            float oyj  = bout[(64 + t) * 15 + j];
            float oysj = bout[(128 + t) * 15 + j];
            float fwj  = s[660 + j];
            pxy += fmaxf(oxj + oyj,  0.0f) * fwj;
            pxs += fmaxf(oxj + oysj, 0.0f) * fwj;
        }
        float e = expf(pxs);
        #pragma unroll
        for (int o = 32; o > 0; o >>= 1) {
            pxy += __shfl_down(pxy, o);
            e   += __shfl_down(e, o);
        }
        if (t == 0) {
            partials[blockIdx.x]        = pxy;
            partials[NBLK + blockIdx.x] = e;
        }
    }
}

// ---------------- finalize: 1 block, 64 lanes ----------------
__global__ __launch_bounds__(64) void k_final(const float* __restrict__ partials,
                                              float* __restrict__ out)
{
    int t = threadIdx.x;
    float sx = partials[t];
    float se = partials[NBLK + t];
    #pragma unroll
    for (int o = 32; o > 0; o >>= 1) {
        sx += __shfl_down(sx, o);
        se += __shfl_down(se, o);
    }
    if (t == 0) out[0] = logf(se / (float)BATCH) - sx / (float)BATCH;
}

extern "C" void kernel_launch(void* const* d_in, const int* in_sizes, int n_in,
                              void* d_out, int out_size, void* d_ws, size_t ws_size,
                              hipStream_t stream)
{
    const float* x    = (const float*)d_in[0];
    const int*   ij   = (const int*)d_in[1];
    const int*   perm = (const int*)d_in[2];
    const float* cw   = (const float*)d_in[3];
    const float* cb   = (const float*)d_in[4];
    const float* xw1  = (const float*)d_in[5];
    const float* xb1  = (const float*)d_in[6];
    const float* xw2  = (const float*)d_in[7];
    const float* xb2  = (const float*)d_in[8];
    const float* xw3  = (const float*)d_in[9];
    const float* xb3  = (const float*)d_in[10];
    const float* yw1  = (const float*)d_in[11];
    const float* yb1  = (const float*)d_in[12];
    const float* yw2  = (const float*)d_in[13];
    const float* yb2  = (const float*)d_in[14];
    const float* yw3  = (const float*)d_in[15];
    const float* yb3  = (const float*)d_in[16];
    const float* fw   = (const float*)d_in[17];
    const float* fb   = (const float*)d_in[18];

    float* partials = (float*)d_ws;   // 128 floats, fully overwritten each launch

    k_fused<<<NBLK, 256, 0, stream>>>(x, ij, perm, cw, cb,
                                      xw1, xb1, xw2, xb2, xw3, xb3,
                                      yw1, yb1, yw2, yb2, yw3, yb3,
                                      fw, fb, partials);
    k_final<<<1, 64, 0, stream>>>(partials, (float*)d_out);
}

// Round 4
// 12.382 us; speedup vs baseline: 1.4504x; 1.1763x over previous
//
#include <hip/hip_runtime.h>
#include <math.h>

#define BATCH 4096
#define IMGD 192
#define HC 64
#define PADV 6
#define NBLK2 256      // blocks for k_fused; one per CU
#define IPB 16         // batch items per block (NBLK2 * IPB == BATCH)

// LDS weight layout offsets (floats):
//  xw1@0(81) xb1@81(9) xw2@90(81) xb2@171(9) xw3@180(135) xb3@315(15)
//  yw1@330   yb1@411   yw2@420    yb2@501    yw3@510      yb3@645
//  fw@660(15) fb@675(1)
__device__ __forceinline__ void branch9(const float* __restrict__ s, int off,
                                        const float* __restrict__ p, float* __restrict__ out)
{
    float v[9];
    #pragma unroll
    for (int j = 0; j < 9; ++j) {
        float a = s[off + 81 + j];
        #pragma unroll
        for (int k = 0; k < 9; ++k) a += p[k] * s[off + j * 9 + k];
        v[j] = p[j] + fmaxf(a, 0.0f);
    }
    float u[9];
    #pragma unroll
    for (int j = 0; j < 9; ++j) {
        float a = s[off + 171 + j];
        #pragma unroll
        for (int k = 0; k < 9; ++k) a += v[k] * s[off + 90 + j * 9 + k];
        u[j] = v[j] + fmaxf(a, 0.0f);
    }
    #pragma unroll
    for (int j = 0; j < 15; ++j) {
        float a = s[off + 315 + j];
        #pragma unroll
        for (int k = 0; k < 9; ++k) a += u[k] * s[off + 180 + j * 9 + k];
        out[j] = a;
    }
}

__global__ __launch_bounds__(256) void k_fused(
    const float* __restrict__ x, const int* __restrict__ ij,
    const int* __restrict__ perm,
    const float* __restrict__ cw, const float* __restrict__ cb,
    const float* __restrict__ xw1, const float* __restrict__ xb1,
    const float* __restrict__ xw2, const float* __restrict__ xb2,
    const float* __restrict__ xw3, const float* __restrict__ xb3,
    const float* __restrict__ yw1, const float* __restrict__ yb1,
    const float* __restrict__ yw2, const float* __restrict__ yb2,
    const float* __restrict__ yw3, const float* __restrict__ yb3,
    const float* __restrict__ fw, const float* __restrict__ fb,
    float* __restrict__ partials)  // [0..255]=sum(pred_xy), [256..511]=sum(exp(pred_x_y))
{
    __shared__ float s[676];
    __shared__ int   pidx[IPB];        // perm index per item
    __shared__ int   ij4[IPB * 4];     // i0, j0, i0p, j0p per item
    __shared__ float lpatch[IPB * 27]; // 0..8 p1, 9..17 p2, 18..26 p2s
    __shared__ float bout[48 * 15];    // [branch*16+item][15]

    int t  = threadIdx.x;
    int b0 = blockIdx.x * IPB;

    // ---- weights -> LDS (independent loads, issue first) ----
    for (int i = t; i < 81; i += 256)  { s[i] = xw1[i];        s[330 + i] = yw1[i];
                                         s[90 + i] = xw2[i];   s[420 + i] = yw2[i]; }
    for (int i = t; i < 135; i += 256) { s[180 + i] = xw3[i];  s[510 + i] = yw3[i]; }
    if (t < 9)  { s[81 + t] = xb1[t];   s[171 + t] = xb2[t];
                  s[411 + t] = yb1[t];  s[501 + t] = yb2[t]; }
    if (t < 15) { s[315 + t] = xb3[t];  s[645 + t] = yb3[t];  s[660 + t] = fw[t]; }
    if (t == 0) s[675] = fb[0];

    float w[9];
    #pragma unroll
    for (int i = 0; i < 9; ++i) w[i] = cw[i];   // uniform -> scalar loads
    float cbias = cb[0];

    // ---- index chase, hoisted once per block ----
    if (t < IPB) pidx[t] = perm[b0 + t];        // coalesced 64 B
    __syncthreads();
    if (t < 2 * IPB) {
        int item = t & (IPB - 1);
        int sel  = t >> 4;                       // 0 = own, 1 = permuted
        int bb   = sel ? pidx[item] : (b0 + item);
        ij4[item * 4 + sel * 2 + 0] = ij[2 * bb];
        ij4[item * 4 + sel * 2 + 1] = ij[2 * bb + 1];
    }
    __syncthreads();

    // ---- gather: <=2 conv outputs per thread, no dependent loads ----
    for (int idx = t; idx < IPB * 27; idx += 256) {
        int item = idx / 27;
        int p    = idx - item * 27;
        int r, c, sel, slot;
        if (p < 18) {
            r = p / 6;  c = p - r * 6;  sel = 0;
            int half = (c >= 3) ? 1 : 0;
            slot = half * 9 + r * 3 + (c - 3 * half);
        } else {
            int q = p - 18;
            r = q / 3;  c = 3 + (q - r * 3);  sel = 1;
            slot = 18 + q;
        }
        int bb = sel ? pidx[item] : (b0 + item);
        int i0 = ij4[item * 4 + sel * 2], j0 = ij4[item * 4 + sel * 2 + 1];
        int rr = i0 - PADV + r;  if (rr < 0) rr += HC;
        int cc = j0 - PADV + c;  if (cc < 0) cc += HC;
        const float* xp = x + (size_t)bb * (IMGD * IMGD)
                            + (size_t)(rr * 3) * IMGD + cc * 3;
        float v = cbias;
        v += xp[0]          * w[0] + xp[1]            * w[1] + xp[2]            * w[2];
        v += xp[IMGD]       * w[3] + xp[IMGD + 1]     * w[4] + xp[IMGD + 2]     * w[5];
        v += xp[2 * IMGD]   * w[6] + xp[2 * IMGD + 1] * w[7] + xp[2 * IMGD + 2] * w[8];
        lpatch[item * 27 + slot] = v;
    }
    __syncthreads();

    // ---- MLP: 3 branches x 16 items ----
    if (t < 48) {
        int item   = t & 15;
        int branch = t >> 4;               // 0: x(p1), 1: y(p2), 2: y(p2s)
        int woff   = (branch == 0) ? 0 : 330;
        int pbase  = item * 27 + branch * 9;
        float p[9];
        #pragma unroll
        for (int k = 0; k < 9; ++k) p[k] = lpatch[pbase + k];
        float o[15];
        branch9(s, woff, p, o);
        #pragma unroll
        for (int j = 0; j < 15; ++j) bout[t * 15 + j] = o[j];
    }
    __syncthreads();

    // ---- head + exp + 16-lane reduce (wave 0) ----
    if (t < IPB) {
        float fbv = s[675];
        float pxy = fbv, pxs = fbv;
        #pragma unroll
        for (int j = 0; j < 15; ++j) {
            float oxj  = bout[t * 15 + j];
            float oyj  = bout[(16 + t) * 15 + j];
            float oysj = bout[(32 + t) * 15 + j];
            float fwj  = s[660 + j];
            pxy += fmaxf(oxj + oyj,  0.0f) * fwj;
            pxs += fmaxf(oxj + oysj, 0.0f) * fwj;
        }
        float e = expf(pxs);
        #pragma unroll
        for (int o = 8; o > 0; o >>= 1) {
            pxy += __shfl_down(pxy, o);
            e   += __shfl_down(e, o);
        }
        if (t == 0) {
            partials[blockIdx.x]         = pxy;
            partials[NBLK2 + blockIdx.x] = e;
        }
    }
}

// ---------------- finalize: 1 block, 256 lanes ----------------
__global__ __launch_bounds__(256) void k_final(const float* __restrict__ partials,
                                               float* __restrict__ out)
{
    __shared__ float r1[4], r2[4];
    int t = threadIdx.x;
    float sx = partials[t];
    float se = partials[NBLK2 + t];
    #pragma unroll
    for (int o = 32; o > 0; o >>= 1) {
        sx += __shfl_down(sx, o);
        se += __shfl_down(se, o);
    }
    int wid = t >> 6, lane = t & 63;
    if (lane == 0) { r1[wid] = sx; r2[wid] = se; }
    __syncthreads();
    if (t == 0) {
        float S  = (r1[0] + r1[1]) + (r1[2] + r1[3]);
        float E  = (r2[0] + r2[1]) + (r2[2] + r2[3]);
        out[0] = logf(E / (float)BATCH) - S / (float)BATCH;
    }
}

extern "C" void kernel_launch(void* const* d_in, const int* in_sizes, int n_in,
                              void* d_out, int out_size, void* d_ws, size_t ws_size,
                              hipStream_t stream)
{
    const float* x    = (const float*)d_in[0];
    const int*   ij   = (const int*)d_in[1];
    const int*   perm = (const int*)d_in[2];
    const float* cw   = (const float*)d_in[3];
    const float* cb   = (const float*)d_in[4];
    const float* xw1  = (const float*)d_in[5];
    const float* xb1  = (const float*)d_in[6];
    const float* xw2  = (const float*)d_in[7];
    const float* xb2  = (const float*)d_in[8];
    const float* xw3  = (const float*)d_in[9];
    const float* xb3  = (const float*)d_in[10];
    const float* yw1  = (const float*)d_in[11];
    const float* yb1  = (const float*)d_in[12];
    const float* yw2  = (const float*)d_in[13];
    const float* yb2  = (const float*)d_in[14];
    const float* yw3  = (const float*)d_in[15];
    const float* yb3  = (const float*)d_in[16];
    const float* fw   = (const float*)d_in[17];
    const float* fb   = (const float*)d_in[18];

    float* partials = (float*)d_ws;   // 512 floats, fully overwritten each launch

    k_fused<<<NBLK2, 256, 0, stream>>>(x, ij, perm, cw, cb,
                                       xw1, xb1, xw2, xb2, xw3, xb3,
                                       yw1, yb1, yw2, yb2, yw3, yb3,
                                       fw, fb, partials);
    k_final<<<1, 256, 0, stream>>>(partials, (float*)d_out);
}